// Round 8
// baseline (206.731 us; speedup 1.0000x reference)
//
#include <hip/hip_runtime.h>
#include <math.h>

#define BATCH 4
#define SEQ   4096
#define EMB   1024
#define HD    128
#define MROWS (BATCH*SEQ)
#define SCALE 0.08838834764831844f   // 1/sqrt(128)
#define CHUNK 10                     // kv-tiles (of 64) per split-KV job
#define NJOBS 119                    // jobs per batch at BQ=128, CHUNK=10
#define MAXC  7                      // max chunks per q-tile = ceil(64/10)

typedef __attribute__((ext_vector_type(8))) short bf16x8;   // MFMA A/B frag (4 VGPR)
typedef __attribute__((ext_vector_type(4))) short short4v;  // 8B LDS store
typedef __attribute__((ext_vector_type(4))) float f32x4;    // MFMA C/D frag
typedef __attribute__((ext_vector_type(4))) int   i32x4;    // 16B copy

static __device__ __forceinline__ unsigned short f2bf(float f) {
    unsigned int u = __float_as_uint(f);
    u += 0x7fff + ((u >> 16) & 1);       // RNE
    return (unsigned short)(u >> 16);
}
static __device__ __forceinline__ float bf2f(unsigned short s) {
    return __uint_as_float((unsigned int)s << 16);
}

// ---------------- W transpose + bf16 (+ fold q-scale) ----------------
__global__ __launch_bounds__(256) void wtrans_kernel(
    const float* __restrict__ Wq, const float* __restrict__ Wk,
    const float* __restrict__ Wv, unsigned short* __restrict__ Wt)
{
    __shared__ __align__(16) unsigned short Xs[16 * 132];
    const int w  = blockIdx.y;
    const float* W = (w == 0) ? Wq : (w == 1) ? Wk : Wv;
    const float sc = (w == 0) ? SCALE : 1.0f;
    unsigned short* dst = Wt + (size_t)w * 131072;
    const int k0 = blockIdx.x * 16;
    const int t  = threadIdx.x;

#pragma unroll
    for (int i = 0; i < 2; ++i) {
        int gg = i * 256 + t;                 // 0..511
        int row = gg >> 5, c4 = gg & 31;
        float4 a = *(const float4*)&W[(size_t)(k0 + row) * HD + c4 * 4];
        short4v p;
        p[0] = (short)f2bf(a.x * sc); p[1] = (short)f2bf(a.y * sc);
        p[2] = (short)f2bf(a.z * sc); p[3] = (short)f2bf(a.w * sc);
        *(short4v*)&Xs[row * 132 + c4 * 4] = p;
    }
    __syncthreads();
    const int n = t >> 1, half = t & 1;
    i32x4 o;
#pragma unroll
    for (int e = 0; e < 4; ++e) {
        unsigned int lo = Xs[(half * 8 + e * 2    ) * 132 + n];
        unsigned int hi = Xs[(half * 8 + e * 2 + 1) * 132 + n];
        o[e] = (int)(lo | (hi << 16));
    }
    *(i32x4*)&dst[(size_t)n * 1024 + k0 + half * 8] = o;
}

// ---------------- Fused QKV: read x once; XOR-swizzled LDS ----------------
// grid 512 x 512 thr (8 waves). Wave ng owns n-tiles 3ng..3ng+2 (48 wave-private W
// rows). All tiles: row stride 64 shorts (128 B), 16B-group g stored at g^(row&7).
__global__ __launch_bounds__(512, 4) void qkv_kernel(
    const float* __restrict__ x, const unsigned short* __restrict__ Wt,
    unsigned short* __restrict__ qb, unsigned short* __restrict__ kb,
    unsigned short* __restrict__ vtb)
{
    __shared__ __align__(16) unsigned short lds[2 * 2048 + 384 * 64];   // 57.3 KB
    unsigned short* xs0 = lds;           // x tile 32 x 64 (buf 0), swizzled
    unsigned short* xs1 = lds + 2048;    // buf 1
    unsigned short* Ws  = lds + 4096;    // W tile 384 x 64, swizzled

    const int t    = threadIdx.x;
    const int lane = t & 63, ng = t >> 6;
    const int quad = lane >> 4, l16 = lane & 15;
    const int m0   = blockIdx.x * 32;
    const int sw   = l16 & 7;            // read-side swizzle key

    f32x4 acc[2][3];
#pragma unroll
    for (int i = 0; i < 2; ++i)
#pragma unroll
        for (int j = 0; j < 3; ++j) acc[i][j] = (f32x4){0.f, 0.f, 0.f, 0.f};

    const int xrow = t >> 3, xg = t & 7;     // staging threads t<256
    const int xoff = xrow * 64 + ((xg ^ (xrow & 7)) * 8);
    // prologue: stage x(kt=0)
    if (t < 256) {
        float4 a  = *(const float4*)&x[(size_t)(m0 + xrow) * EMB + xg * 8];
        float4 b2 = *(const float4*)&x[(size_t)(m0 + xrow) * EMB + xg * 8 + 4];
        i32x4 p;
        p[0] = (int)((unsigned)f2bf(a.x)  | ((unsigned)f2bf(a.y)  << 16));
        p[1] = (int)((unsigned)f2bf(a.z)  | ((unsigned)f2bf(a.w)  << 16));
        p[2] = (int)((unsigned)f2bf(b2.x) | ((unsigned)f2bf(b2.y) << 16));
        p[3] = (int)((unsigned)f2bf(b2.z) | ((unsigned)f2bf(b2.w) << 16));
        *(i32x4*)&xs0[xoff] = p;
    }
    __syncthreads();

    for (int kt = 0; kt < EMB; kt += 64) {
        unsigned short* xb = (kt & 64) ? xs1 : xs0;
        unsigned short* xn = (kt & 64) ? xs0 : xs1;
        // wave-private W staging (rows 48*ng .. +47), swizzled writes
#pragma unroll
        for (int i = 0; i < 6; ++i) {
            int rowl = ng * 48 + i * 8 + (lane >> 3);
            int g    = lane & 7;
            *(i32x4*)&Ws[rowl * 64 + ((g ^ (rowl & 7)) * 8)] =
                *(const i32x4*)&Wt[(size_t)rowl * 1024 + kt + g * 8];
        }
        // prefetch next x tile into the other buffer
        if (t < 256 && kt + 64 < EMB) {
            float4 a  = *(const float4*)&x[(size_t)(m0 + xrow) * EMB + kt + 64 + xg * 8];
            float4 b2 = *(const float4*)&x[(size_t)(m0 + xrow) * EMB + kt + 64 + xg * 8 + 4];
            i32x4 p;
            p[0] = (int)((unsigned)f2bf(a.x)  | ((unsigned)f2bf(a.y)  << 16));
            p[1] = (int)((unsigned)f2bf(a.z)  | ((unsigned)f2bf(a.w)  << 16));
            p[2] = (int)((unsigned)f2bf(b2.x) | ((unsigned)f2bf(b2.y) << 16));
            p[3] = (int)((unsigned)f2bf(b2.z) | ((unsigned)f2bf(b2.w) << 16));
            *(i32x4*)&xn[xoff] = p;
        }
        // compute
#pragma unroll
        for (int ks = 0; ks < 2; ++ks) {
            bf16x8 aA[2], aB[3];
#pragma unroll
            for (int mt = 0; mt < 2; ++mt)
                aA[mt] = *(const bf16x8*)&xb[(mt * 16 + l16) * 64 +
                                             (((ks * 4 + quad) ^ sw) * 8)];
#pragma unroll
            for (int jt = 0; jt < 3; ++jt)
                aB[jt] = *(const bf16x8*)&Ws[((ng * 3 + jt) * 16 + l16) * 64 +
                                             (((ks * 4 + quad) ^ sw) * 8)];
#pragma unroll
            for (int mt = 0; mt < 2; ++mt)
#pragma unroll
                for (int jt = 0; jt < 3; ++jt)
                    acc[mt][jt] = __builtin_amdgcn_mfma_f32_16x16x32_bf16(
                        aA[mt], aB[jt], acc[mt][jt], 0, 0, 0);
        }
        __syncthreads();
    }

    // ---- epilogue: scatter to LDS (per-matrix layout), then coalesced copy out ----
    unsigned short* Cq = lds;                 // [32][136]
    unsigned short* Ck = lds + 32 * 136;      // [32][136]
    unsigned short* Cv = lds + 2 * 32 * 136;  // [128][40] transposed
#pragma unroll
    for (int mt = 0; mt < 2; ++mt)
#pragma unroll
        for (int jt = 0; jt < 3; ++jt) {
            int nt = ng * 3 + jt;
            int wm = nt >> 3, nl = nt & 7;
            if (wm < 2) {
                unsigned short* C = (wm == 0) ? Cq : Ck;
#pragma unroll
                for (int rr = 0; rr < 4; ++rr)
                    C[(mt * 16 + quad * 4 + rr) * 136 + nl * 16 + l16] =
                        f2bf(acc[mt][jt][rr]);
            } else {
                short4v p;
                p[0] = (short)f2bf(acc[mt][jt][0]); p[1] = (short)f2bf(acc[mt][jt][1]);
                p[2] = (short)f2bf(acc[mt][jt][2]); p[3] = (short)f2bf(acc[mt][jt][3]);
                *(short4v*)&Cv[(nl * 16 + l16) * 40 + mt * 16 + quad * 4] = p;
            }
        }
    __syncthreads();
    {   // q, k: 32 x 128 each -> 512 i32x4, one per thread
        int row = t >> 4, seg = t & 15;
        *(i32x4*)&qb[((size_t)(m0 + row)) * HD + seg * 8] = *(const i32x4*)&Cq[row * 136 + seg * 8];
        *(i32x4*)&kb[((size_t)(m0 + row)) * HD + seg * 8] = *(const i32x4*)&Ck[row * 136 + seg * 8];
    }
    {   // v^T: 128 x 32 -> 512 i32x4, one per thread
        const int b = m0 >> 12, s0 = m0 & 4095;
        int h = t >> 2, seg = t & 3;
        *(i32x4*)&vtb[(size_t)b * (HD * SEQ) + (size_t)h * SEQ + s0 + seg * 8] =
            *(const i32x4*)&Cv[h * 40 + seg * 8];
    }
}

// ---------------- Flash attention: split-KV, BQ=128, XOR-swizzled LDS ----------------
// grid 480 x 512 thr. XCD-batch affinity: slot=bx&7, batch=slot>>1.
// Ks 64x128, Vt 128x64, Pt 128x64 — all swizzled, 48 KB total -> 3 blocks/CU.
__global__ __launch_bounds__(512, 6) void flash_kernel(
    const unsigned short* __restrict__ qb, const unsigned short* __restrict__ kb,
    const unsigned short* __restrict__ vtb, unsigned short* __restrict__ Opart,
    float* __restrict__ mbuf, float* __restrict__ lbuf)
{
    __shared__ __align__(16) unsigned short Ks[64 * 128];    // 16 KB
    __shared__ __align__(16) unsigned short Vt[128 * 64];    // 16 KB
    __shared__ __align__(16) unsigned short Pt[128 * 64];    // 16 KB

    const int bx   = blockIdx.x;
    const int slot = bx & 7, pp = bx >> 3;
    const int b    = slot >> 1;
    const int jj   = pp * 2 + (slot & 1);
    if (jj >= NJOBS) return;                 // dummy pad blocks

    const int t    = threadIdx.x;
    const int lane = t & 63, w = t >> 6;     // 8 waves
    const int quad = lane >> 4, l16 = lane & 15;
    const int sw   = l16 & 7;                // read-side swizzle key

    // decode jj -> (qi, c): q-tile qi has ceil((qi+1)/5) chunks
    int qi = 0, s = 0;
    for (qi = 0; qi < 32; ++qi) {
        int cnt = (qi + 5) / 5;
        if (jj < s + cnt) break;
        s += cnt;
    }
    const int c    = jj - s;
    const int qrow = qi * 128 + w * 16 + l16;
    const int jmax = 2 * qi + 2;
    const int jbeg = c * CHUNK;
    const int jend = min(jbeg + CHUNK, jmax);

    bf16x8 qf[4];
    {
        const unsigned short* qp = qb + ((size_t)b * SEQ + qrow) * HD;
#pragma unroll
        for (int ks = 0; ks < 4; ++ks)
            qf[ks] = *(const bf16x8*)&qp[ks * 32 + quad * 8];
    }

    f32x4 O[8];
#pragma unroll
    for (int i = 0; i < 8; ++i) O[i] = (f32x4){0.f, 0.f, 0.f, 0.f};
    float m_run = -1e30f, l_run = 0.f;

    const unsigned short* kbb  = kb  + (size_t)b * SEQ * HD;
    const unsigned short* vtbb = vtb + (size_t)b * HD * SEQ;

    for (int j0 = jbeg; j0 < jend; ++j0) {
        __syncthreads();   // prior iteration's reads of Ks/Vt complete
#pragma unroll
        for (int i = 0; i < 2; ++i) {
            int gg = i * 512 + t;            // K: 1024 chunks of 16B; row=gg>>4, g=gg&15
            i32x4 kd = *(const i32x4*)&kbb[(size_t)j0 * 64 * HD + (size_t)gg * 8];
            *(i32x4*)&Ks[(gg >> 4) * 128 + (((gg & 15) ^ ((gg >> 4) & 7)) * 8)] = kd;
        }
#pragma unroll
        for (int i = 0; i < 2; ++i) {
            int gg = i * 512 + t;            // V^T: row=gg>>3, g=gg&7
            i32x4 vd = *(const i32x4*)&vtbb[(size_t)(gg >> 3) * SEQ + j0 * 64 + (gg & 7) * 8];
            *(i32x4*)&Vt[(gg >> 3) * 64 + (((gg & 7) ^ ((gg >> 3) & 7)) * 8)] = vd;
        }
        __syncthreads();

        // fully-masked tile for this wave? -> skip compute
        if (j0 * 64 > qi * 128 + w * 16 + 15) continue;

        // ---- S^T = K . Q^T ----
        f32x4 st[4];
#pragma unroll
        for (int mt = 0; mt < 4; ++mt) {
            f32x4 a = (f32x4){0.f, 0.f, 0.f, 0.f};
#pragma unroll
            for (int ks = 0; ks < 4; ++ks) {
                bf16x8 kf = *(const bf16x8*)&Ks[(mt * 16 + l16) * 128 +
                                                (((ks * 4 + quad) ^ sw) * 8)];
                a = __builtin_amdgcn_mfma_f32_16x16x32_bf16(kf, qf[ks], a, 0, 0, 0);
            }
            st[mt] = a;
        }

        // ---- causal mask (skip when tile fully valid for this wave) ----
        if (j0 * 64 + 63 > qi * 128 + w * 16) {
#pragma unroll
            for (int mt = 0; mt < 4; ++mt)
#pragma unroll
                for (int rr = 0; rr < 4; ++rr) {
                    int kv = j0 * 64 + mt * 16 + quad * 4 + rr;
                    if (kv > qrow) st[mt][rr] = -1e30f;
                }
        }
        // Rows with zero valid entries yield m=-1e30 garbage partials;
        // combine neutralizes them via wgt = exp(-1e30 - M) = 0.

        // ---- online softmax (lane owns one q-row) ----
        float mx = -1e30f;
#pragma unroll
        for (int mt = 0; mt < 4; ++mt)
#pragma unroll
            for (int rr = 0; rr < 4; ++rr) mx = fmaxf(mx, st[mt][rr]);
        mx = fmaxf(mx, __shfl_xor(mx, 16));
        mx = fmaxf(mx, __shfl_xor(mx, 32));
        const float m_new = fmaxf(m_run, mx);
        const float alpha = __expf(m_run - m_new);
        float psum = 0.f;
#pragma unroll
        for (int mt = 0; mt < 4; ++mt)
#pragma unroll
            for (int rr = 0; rr < 4; ++rr) {
                float p = __expf(st[mt][rr] - m_new);
                st[mt][rr] = p;
                psum += p;
            }
        psum += __shfl_xor(psum, 16);
        psum += __shfl_xor(psum, 32);
        m_run = m_new;
        l_run = l_run * alpha + psum;

        // ---- P^T -> LDS (wave-private rows; swizzled 8B writes) ----
        {
            const int r = w * 16 + l16;
#pragma unroll
            for (int mt = 0; mt < 4; ++mt) {
                short4v p;
                p[0] = (short)f2bf(st[mt][0]); p[1] = (short)f2bf(st[mt][1]);
                p[2] = (short)f2bf(st[mt][2]); p[3] = (short)f2bf(st[mt][3]);
                int g = mt * 2 + (quad >> 1);              // 16B-group of col mt*16+quad*4
                *(short4v*)&Pt[r * 64 + ((g ^ (r & 7)) * 8) + (quad & 1) * 4] = p;
            }
        }

#pragma unroll
        for (int i = 0; i < 8; ++i) {
            O[i][0] *= alpha; O[i][1] *= alpha; O[i][2] *= alpha; O[i][3] *= alpha;
        }

        // ---- O^T += V^T . P^T ----
        const int r = w * 16 + l16;
        bf16x8 pf0 = *(const bf16x8*)&Pt[r * 64 + (((0 * 4 + quad) ^ (r & 7)) * 8)];
        bf16x8 pf1 = *(const bf16x8*)&Pt[r * 64 + (((1 * 4 + quad) ^ (r & 7)) * 8)];
#pragma unroll
        for (int mt = 0; mt < 8; ++mt) {
            bf16x8 vf0 = *(const bf16x8*)&Vt[(mt * 16 + l16) * 64 + (((0 * 4 + quad) ^ sw) * 8)];
            bf16x8 vf1 = *(const bf16x8*)&Vt[(mt * 16 + l16) * 64 + (((1 * 4 + quad) ^ sw) * 8)];
            O[mt] = __builtin_amdgcn_mfma_f32_16x16x32_bf16(vf0, pf0, O[mt], 0, 0, 0);
            O[mt] = __builtin_amdgcn_mfma_f32_16x16x32_bf16(vf1, pf1, O[mt], 0, 0, 0);
        }
    }

    // ---- partial epilogue: unnormalized O (bf16) + m,l ----
    const int r = w * 16 + l16;
    const size_t jobbase = (size_t)b * NJOBS + jj;
    unsigned short* po = Opart + jobbase * (128 * 128) + (size_t)r * 128;
#pragma unroll
    for (int mt = 0; mt < 8; ++mt) {
        short4v p;
        p[0] = (short)f2bf(O[mt][0]); p[1] = (short)f2bf(O[mt][1]);
        p[2] = (short)f2bf(O[mt][2]); p[3] = (short)f2bf(O[mt][3]);
        *(short4v*)&po[mt * 16 + quad * 4] = p;
    }
    if (quad == 0) {
        mbuf[jobbase * 128 + r] = m_run;
        lbuf[jobbase * 128 + r] = l_run;
    }
}

// ---------------- Combine partials ----------------
// grid (32, 4) x 512 thr: thread -> q-row t>>2 (0..127), 32 head cols at (t&3)*32.
__global__ __launch_bounds__(512) void combine_kernel(
    const unsigned short* __restrict__ Opart, const float* __restrict__ mbuf,
    const float* __restrict__ lbuf, float* __restrict__ out)
{
    const int qi = blockIdx.x, b = blockIdx.y;
    const int nc = (qi + 5) / 5;
    int j0 = 0;
    for (int q = 0; q < qi; ++q) j0 += (q + 5) / 5;
    const int t = threadIdx.x;
    const int row = t >> 2, cg = (t & 3) * 32;

    float mv[MAXC], lv[MAXC];
    float M = -1e30f;
#pragma unroll
    for (int c2 = 0; c2 < MAXC; ++c2) {
        if (c2 < nc) {
            const size_t jb = (size_t)b * NJOBS + j0 + c2;
            mv[c2] = mbuf[jb * 128 + row];
            lv[c2] = lbuf[jb * 128 + row];
            M = fmaxf(M, mv[c2]);
        } else { mv[c2] = -1e30f; lv[c2] = 0.f; }
    }
    float L = 0.f;
#pragma unroll
    for (int c2 = 0; c2 < MAXC; ++c2)
        if (c2 < nc) L += __expf(mv[c2] - M) * lv[c2];
    const float Linv = 1.0f / L;

    float acc[32];
#pragma unroll
    for (int i = 0; i < 32; ++i) acc[i] = 0.f;
#pragma unroll
    for (int c2 = 0; c2 < MAXC; ++c2) {
        if (c2 < nc) {
            const float wgt = __expf(mv[c2] - M) * Linv;
            const unsigned short* po = Opart + ((size_t)b * NJOBS + j0 + c2) * (128 * 128) +
                                       (size_t)row * 128 + cg;
#pragma unroll
            for (int i = 0; i < 4; ++i) {
                i32x4 d = *(const i32x4*)&po[i * 8];
#pragma unroll
                for (int e = 0; e < 4; ++e) {
                    unsigned int u = (unsigned int)d[e];
                    acc[i * 8 + e * 2]     = fmaf(wgt, bf2f((unsigned short)(u & 0xffff)), acc[i * 8 + e * 2]);
                    acc[i * 8 + e * 2 + 1] = fmaf(wgt, bf2f((unsigned short)(u >> 16)),   acc[i * 8 + e * 2 + 1]);
                }
            }
        }
    }
    float* op = out + ((size_t)b * SEQ + qi * 128 + row) * HD + cg;
#pragma unroll
    for (int i = 0; i < 8; ++i) {
        float4 res;
        res.x = acc[i * 4]; res.y = acc[i * 4 + 1];
        res.z = acc[i * 4 + 2]; res.w = acc[i * 4 + 3];
        *(float4*)&op[i * 4] = res;
    }
}

extern "C" void kernel_launch(void* const* d_in, const int* in_sizes, int n_in,
                              void* d_out, int out_size, void* d_ws, size_t ws_size,
                              hipStream_t stream) {
    const float* x  = (const float*)d_in[0];
    const float* Wq = (const float*)d_in[1];
    const float* Wk = (const float*)d_in[2];
    const float* Wv = (const float*)d_in[3];

    unsigned short* qb    = (unsigned short*)d_ws;          // [16384][128] bf16
    unsigned short* kb    = qb  + (size_t)MROWS * HD;       // [16384][128] bf16
    unsigned short* vtb   = kb  + (size_t)MROWS * HD;       // [4][128][4096] bf16
    unsigned short* Wt    = vtb + (size_t)MROWS * HD;       // [3][128][1024] bf16
    unsigned short* Opart = Wt  + (size_t)3 * HD * EMB;     // [4][119][128][128] bf16
    float* mbuf = (float*)(Opart + (size_t)BATCH * NJOBS * 128 * 128);
    float* lbuf = mbuf + (size_t)BATCH * NJOBS * 128;
    float* out = (float*)d_out;

    wtrans_kernel <<<dim3(64, 3),  dim3(256), 0, stream>>>(Wq, Wk, Wv, Wt);
    qkv_kernel    <<<dim3(512),    dim3(512), 0, stream>>>(x, Wt, qb, kb, vtb);
    flash_kernel  <<<dim3(480),    dim3(512), 0, stream>>>(qb, kb, vtb, Opart, mbuf, lbuf);
    combine_kernel<<<dim3(32, 4),  dim3(512), 0, stream>>>(Opart, mbuf, lbuf, out);
}

// Round 9
// 201.019 us; speedup vs baseline: 1.0284x; 1.0284x over previous
//
#include <hip/hip_runtime.h>
#include <math.h>

#define BATCH 4
#define SEQ   4096
#define EMB   1024
#define HD    128
#define MROWS (BATCH*SEQ)
#define SCALE 0.08838834764831844f   // 1/sqrt(128)
#define CHUNK 10                     // kv-tiles (of 64) per split-KV job
#define NJOBS 119                    // jobs per batch at BQ=128, CHUNK=10
#define MAXC  7                      // max chunks per q-tile = ceil(64/10)

typedef __attribute__((ext_vector_type(8))) short bf16x8;   // MFMA A/B frag (4 VGPR)
typedef __attribute__((ext_vector_type(4))) short short4v;  // 8B LDS store
typedef __attribute__((ext_vector_type(4))) float f32x4;    // MFMA C/D frag
typedef __attribute__((ext_vector_type(4))) int   i32x4;    // 16B copy

static __device__ __forceinline__ unsigned short f2bf(float f) {
    unsigned int u = __float_as_uint(f);
    u += 0x7fff + ((u >> 16) & 1);       // RNE
    return (unsigned short)(u >> 16);
}
static __device__ __forceinline__ float bf2f(unsigned short s) {
    return __uint_as_float((unsigned int)s << 16);
}

// ---------------- W transpose + bf16 (+ fold q-scale) ----------------
__global__ __launch_bounds__(256) void wtrans_kernel(
    const float* __restrict__ Wq, const float* __restrict__ Wk,
    const float* __restrict__ Wv, unsigned short* __restrict__ Wt)
{
    __shared__ __align__(16) unsigned short Xs[16 * 132];
    const int w  = blockIdx.y;
    const float* W = (w == 0) ? Wq : (w == 1) ? Wk : Wv;
    const float sc = (w == 0) ? SCALE : 1.0f;
    unsigned short* dst = Wt + (size_t)w * 131072;
    const int k0 = blockIdx.x * 16;
    const int t  = threadIdx.x;

#pragma unroll
    for (int i = 0; i < 2; ++i) {
        int gg = i * 256 + t;                 // 0..511
        int row = gg >> 5, c4 = gg & 31;
        float4 a = *(const float4*)&W[(size_t)(k0 + row) * HD + c4 * 4];
        short4v p;
        p[0] = (short)f2bf(a.x * sc); p[1] = (short)f2bf(a.y * sc);
        p[2] = (short)f2bf(a.z * sc); p[3] = (short)f2bf(a.w * sc);
        *(short4v*)&Xs[row * 132 + c4 * 4] = p;
    }
    __syncthreads();
    const int n = t >> 1, half = t & 1;
    i32x4 o;
#pragma unroll
    for (int e = 0; e < 4; ++e) {
        unsigned int lo = Xs[(half * 8 + e * 2    ) * 132 + n];
        unsigned int hi = Xs[(half * 8 + e * 2 + 1) * 132 + n];
        o[e] = (int)(lo | (hi << 16));
    }
    *(i32x4*)&dst[(size_t)n * 1024 + k0 + half * 8] = o;
}

// ---------------- Fused QKV: read x once; XOR-swizzled LDS ----------------
// (unchanged from R8 — isolating the flash change this round)
__global__ __launch_bounds__(512, 4) void qkv_kernel(
    const float* __restrict__ x, const unsigned short* __restrict__ Wt,
    unsigned short* __restrict__ qb, unsigned short* __restrict__ kb,
    unsigned short* __restrict__ vtb)
{
    __shared__ __align__(16) unsigned short lds[2 * 2048 + 384 * 64];   // 57.3 KB
    unsigned short* xs0 = lds;           // x tile 32 x 64 (buf 0), swizzled
    unsigned short* xs1 = lds + 2048;    // buf 1
    unsigned short* Ws  = lds + 4096;    // W tile 384 x 64, swizzled

    const int t    = threadIdx.x;
    const int lane = t & 63, ng = t >> 6;
    const int quad = lane >> 4, l16 = lane & 15;
    const int m0   = blockIdx.x * 32;
    const int sw   = l16 & 7;            // read-side swizzle key

    f32x4 acc[2][3];
#pragma unroll
    for (int i = 0; i < 2; ++i)
#pragma unroll
        for (int j = 0; j < 3; ++j) acc[i][j] = (f32x4){0.f, 0.f, 0.f, 0.f};

    const int xrow = t >> 3, xg = t & 7;     // staging threads t<256
    const int xoff = xrow * 64 + ((xg ^ (xrow & 7)) * 8);
    // prologue: stage x(kt=0)
    if (t < 256) {
        float4 a  = *(const float4*)&x[(size_t)(m0 + xrow) * EMB + xg * 8];
        float4 b2 = *(const float4*)&x[(size_t)(m0 + xrow) * EMB + xg * 8 + 4];
        i32x4 p;
        p[0] = (int)((unsigned)f2bf(a.x)  | ((unsigned)f2bf(a.y)  << 16));
        p[1] = (int)((unsigned)f2bf(a.z)  | ((unsigned)f2bf(a.w)  << 16));
        p[2] = (int)((unsigned)f2bf(b2.x) | ((unsigned)f2bf(b2.y) << 16));
        p[3] = (int)((unsigned)f2bf(b2.z) | ((unsigned)f2bf(b2.w) << 16));
        *(i32x4*)&xs0[xoff] = p;
    }
    __syncthreads();

    for (int kt = 0; kt < EMB; kt += 64) {
        unsigned short* xb = (kt & 64) ? xs1 : xs0;
        unsigned short* xn = (kt & 64) ? xs0 : xs1;
        // wave-private W staging (rows 48*ng .. +47), swizzled writes
#pragma unroll
        for (int i = 0; i < 6; ++i) {
            int rowl = ng * 48 + i * 8 + (lane >> 3);
            int g    = lane & 7;
            *(i32x4*)&Ws[rowl * 64 + ((g ^ (rowl & 7)) * 8)] =
                *(const i32x4*)&Wt[(size_t)rowl * 1024 + kt + g * 8];
        }
        // prefetch next x tile into the other buffer
        if (t < 256 && kt + 64 < EMB) {
            float4 a  = *(const float4*)&x[(size_t)(m0 + xrow) * EMB + kt + 64 + xg * 8];
            float4 b2 = *(const float4*)&x[(size_t)(m0 + xrow) * EMB + kt + 64 + xg * 8 + 4];
            i32x4 p;
            p[0] = (int)((unsigned)f2bf(a.x)  | ((unsigned)f2bf(a.y)  << 16));
            p[1] = (int)((unsigned)f2bf(a.z)  | ((unsigned)f2bf(a.w)  << 16));
            p[2] = (int)((unsigned)f2bf(b2.x) | ((unsigned)f2bf(b2.y) << 16));
            p[3] = (int)((unsigned)f2bf(b2.z) | ((unsigned)f2bf(b2.w) << 16));
            *(i32x4*)&xn[xoff] = p;
        }
        // compute
#pragma unroll
        for (int ks = 0; ks < 2; ++ks) {
            bf16x8 aA[2], aB[3];
#pragma unroll
            for (int mt = 0; mt < 2; ++mt)
                aA[mt] = *(const bf16x8*)&xb[(mt * 16 + l16) * 64 +
                                             (((ks * 4 + quad) ^ sw) * 8)];
#pragma unroll
            for (int jt = 0; jt < 3; ++jt)
                aB[jt] = *(const bf16x8*)&Ws[((ng * 3 + jt) * 16 + l16) * 64 +
                                             (((ks * 4 + quad) ^ sw) * 8)];
#pragma unroll
            for (int mt = 0; mt < 2; ++mt)
#pragma unroll
                for (int jt = 0; jt < 3; ++jt)
                    acc[mt][jt] = __builtin_amdgcn_mfma_f32_16x16x32_bf16(
                        aA[mt], aB[jt], acc[mt][jt], 0, 0, 0);
        }
        __syncthreads();
    }

    // ---- epilogue: scatter to LDS (per-matrix layout), then coalesced copy out ----
    unsigned short* Cq = lds;                 // [32][136]
    unsigned short* Ck = lds + 32 * 136;      // [32][136]
    unsigned short* Cv = lds + 2 * 32 * 136;  // [128][40] transposed
#pragma unroll
    for (int mt = 0; mt < 2; ++mt)
#pragma unroll
        for (int jt = 0; jt < 3; ++jt) {
            int nt = ng * 3 + jt;
            int wm = nt >> 3, nl = nt & 7;
            if (wm < 2) {
                unsigned short* C = (wm == 0) ? Cq : Ck;
#pragma unroll
                for (int rr = 0; rr < 4; ++rr)
                    C[(mt * 16 + quad * 4 + rr) * 136 + nl * 16 + l16] =
                        f2bf(acc[mt][jt][rr]);
            } else {
                short4v p;
                p[0] = (short)f2bf(acc[mt][jt][0]); p[1] = (short)f2bf(acc[mt][jt][1]);
                p[2] = (short)f2bf(acc[mt][jt][2]); p[3] = (short)f2bf(acc[mt][jt][3]);
                *(short4v*)&Cv[(nl * 16 + l16) * 40 + mt * 16 + quad * 4] = p;
            }
        }
    __syncthreads();
    {   // q, k: 32 x 128 each -> 512 i32x4, one per thread
        int row = t >> 4, seg = t & 15;
        *(i32x4*)&qb[((size_t)(m0 + row)) * HD + seg * 8] = *(const i32x4*)&Cq[row * 136 + seg * 8];
        *(i32x4*)&kb[((size_t)(m0 + row)) * HD + seg * 8] = *(const i32x4*)&Ck[row * 136 + seg * 8];
    }
    {   // v^T: 128 x 32 -> 512 i32x4, one per thread
        const int b = m0 >> 12, s0 = m0 & 4095;
        int h = t >> 2, seg = t & 3;
        *(i32x4*)&vtb[(size_t)b * (HD * SEQ) + (size_t)h * SEQ + s0 + seg * 8] =
            *(const i32x4*)&Cv[h * 40 + seg * 8];
    }
}

// ---------------- Flash: split-KV, BQ=128, 4 waves x 32 q-rows (2 halves) ----------------
// grid 480 x 256 thr. Each wave owns 32 q-rows as two 16-row halves; every kf/vf
// LDS fragment read feeds 2 MFMAs (one per half) -> ~halves LDS frag traffic.
// XOR-swizzled LDS (48 KB), XCD-batch affinity. All 16x16x32 verified layouts.
__global__ __launch_bounds__(256, 3) void flash_kernel(
    const unsigned short* __restrict__ qb, const unsigned short* __restrict__ kb,
    const unsigned short* __restrict__ vtb, unsigned short* __restrict__ Opart,
    float* __restrict__ mbuf, float* __restrict__ lbuf)
{
    __shared__ __align__(16) unsigned short Ks[64 * 128];    // 16 KB
    __shared__ __align__(16) unsigned short Vt[128 * 64];    // 16 KB
    __shared__ __align__(16) unsigned short Pt[128 * 64];    // 16 KB

    const int bx   = blockIdx.x;
    const int slot = bx & 7, pp = bx >> 3;
    const int b    = slot >> 1;
    const int jj   = pp * 2 + (slot & 1);
    if (jj >= NJOBS) return;                 // dummy pad blocks

    const int t    = threadIdx.x;
    const int lane = t & 63, w = t >> 6;     // 4 waves
    const int quad = lane >> 4, l16 = lane & 15;
    const int sw   = l16 & 7;                // read-side swizzle key

    // decode jj -> (qi, c): q-tile qi has ceil((qi+1)/5) chunks
    int qi = 0, s = 0;
    for (qi = 0; qi < 32; ++qi) {
        int cnt = (qi + 5) / 5;
        if (jj < s + cnt) break;
        s += cnt;
    }
    const int c     = jj - s;
    const int qbase = qi * 128 + w * 32;     // this wave's 32 q-rows
    const int jmax  = 2 * qi + 2;
    const int jbeg  = c * CHUNK;
    const int jend  = min(jbeg + CHUNK, jmax);

    bf16x8 qf[2][4];
#pragma unroll
    for (int h = 0; h < 2; ++h) {
        const unsigned short* qp = qb + ((size_t)b * SEQ + qbase + h * 16 + l16) * HD;
#pragma unroll
        for (int ks = 0; ks < 4; ++ks)
            qf[h][ks] = *(const bf16x8*)&qp[ks * 32 + quad * 8];
    }

    f32x4 O[2][8];
#pragma unroll
    for (int h = 0; h < 2; ++h)
#pragma unroll
        for (int i = 0; i < 8; ++i) O[h][i] = (f32x4){0.f, 0.f, 0.f, 0.f};
    float m_run[2] = {-1e30f, -1e30f}, l_run[2] = {0.f, 0.f};

    const unsigned short* kbb  = kb  + (size_t)b * SEQ * HD;
    const unsigned short* vtbb = vtb + (size_t)b * HD * SEQ;

    for (int j0 = jbeg; j0 < jend; ++j0) {
        __syncthreads();   // prior iteration's reads of Ks/Vt complete
#pragma unroll
        for (int i = 0; i < 4; ++i) {
            int gg = i * 256 + t;            // K: 1024 chunks of 16B; row=gg>>4, g=gg&15
            i32x4 kd = *(const i32x4*)&kbb[(size_t)j0 * 64 * HD + (size_t)gg * 8];
            *(i32x4*)&Ks[(gg >> 4) * 128 + (((gg & 15) ^ ((gg >> 4) & 7)) * 8)] = kd;
        }
#pragma unroll
        for (int i = 0; i < 4; ++i) {
            int gg = i * 256 + t;            // V^T: row=gg>>3, g=gg&7
            i32x4 vd = *(const i32x4*)&vtbb[(size_t)(gg >> 3) * SEQ + j0 * 64 + (gg & 7) * 8];
            *(i32x4*)&Vt[(gg >> 3) * 64 + (((gg & 7) ^ ((gg >> 3) & 7)) * 8)] = vd;
        }
        __syncthreads();

        // fully-masked tile for this wave? -> skip compute (wave-uniform)
        if (j0 * 64 > qbase + 31) continue;

        // ---- S^T = K . Q^T  (each kf read feeds both q-halves) ----
        f32x4 st[2][4];
#pragma unroll
        for (int mt = 0; mt < 4; ++mt) { st[0][mt] = (f32x4){0.f,0.f,0.f,0.f};
                                         st[1][mt] = (f32x4){0.f,0.f,0.f,0.f}; }
#pragma unroll
        for (int mt = 0; mt < 4; ++mt)
#pragma unroll
            for (int ks = 0; ks < 4; ++ks) {
                bf16x8 kf = *(const bf16x8*)&Ks[(mt * 16 + l16) * 128 +
                                                (((ks * 4 + quad) ^ sw) * 8)];
                st[0][mt] = __builtin_amdgcn_mfma_f32_16x16x32_bf16(kf, qf[0][ks], st[0][mt], 0, 0, 0);
                st[1][mt] = __builtin_amdgcn_mfma_f32_16x16x32_bf16(kf, qf[1][ks], st[1][mt], 0, 0, 0);
            }

        // ---- per-half: causal mask, online softmax, P^T -> LDS ----
        float alpha[2];
#pragma unroll
        for (int h = 0; h < 2; ++h) {
            const int qrow = qbase + h * 16 + l16;
            if (j0 * 64 + 63 > qbase + h * 16) {
#pragma unroll
                for (int mt = 0; mt < 4; ++mt)
#pragma unroll
                    for (int rr = 0; rr < 4; ++rr) {
                        int kv = j0 * 64 + mt * 16 + quad * 4 + rr;
                        if (kv > qrow) st[h][mt][rr] = -1e30f;
                    }
            }
            float mx = -1e30f;
#pragma unroll
            for (int mt = 0; mt < 4; ++mt)
#pragma unroll
                for (int rr = 0; rr < 4; ++rr) mx = fmaxf(mx, st[h][mt][rr]);
            mx = fmaxf(mx, __shfl_xor(mx, 16));
            mx = fmaxf(mx, __shfl_xor(mx, 32));
            const float m_new = fmaxf(m_run[h], mx);
            alpha[h] = __expf(m_run[h] - m_new);
            float psum = 0.f;
#pragma unroll
            for (int mt = 0; mt < 4; ++mt)
#pragma unroll
                for (int rr = 0; rr < 4; ++rr) {
                    float p = __expf(st[h][mt][rr] - m_new);
                    st[h][mt][rr] = p;
                    psum += p;
                }
            psum += __shfl_xor(psum, 16);
            psum += __shfl_xor(psum, 32);
            m_run[h] = m_new;
            l_run[h] = l_run[h] * alpha[h] + psum;

            const int r = w * 32 + h * 16 + l16;          // r&7 == sw
#pragma unroll
            for (int mt = 0; mt < 4; ++mt) {
                short4v p;
                p[0] = (short)f2bf(st[h][mt][0]); p[1] = (short)f2bf(st[h][mt][1]);
                p[2] = (short)f2bf(st[h][mt][2]); p[3] = (short)f2bf(st[h][mt][3]);
                int g = mt * 2 + (quad >> 1);
                *(short4v*)&Pt[r * 64 + ((g ^ sw) * 8) + (quad & 1) * 4] = p;
            }
        }

        // ---- rescale O ----
#pragma unroll
        for (int h = 0; h < 2; ++h)
#pragma unroll
            for (int i = 0; i < 8; ++i) {
                O[h][i][0] *= alpha[h]; O[h][i][1] *= alpha[h];
                O[h][i][2] *= alpha[h]; O[h][i][3] *= alpha[h];
            }

        // ---- O^T += V^T . P^T  (each vf read feeds both halves) ----
        bf16x8 pf[2][2];
#pragma unroll
        for (int h = 0; h < 2; ++h) {
            const int r = w * 32 + h * 16 + l16;
            pf[h][0] = *(const bf16x8*)&Pt[r * 64 + (((0 + quad) ^ sw) * 8)];
            pf[h][1] = *(const bf16x8*)&Pt[r * 64 + (((4 + quad) ^ sw) * 8)];
        }
#pragma unroll
        for (int mt = 0; mt < 8; ++mt) {
            bf16x8 vf0 = *(const bf16x8*)&Vt[(mt * 16 + l16) * 64 + (((0 + quad) ^ sw) * 8)];
            bf16x8 vf1 = *(const bf16x8*)&Vt[(mt * 16 + l16) * 64 + (((4 + quad) ^ sw) * 8)];
#pragma unroll
            for (int h = 0; h < 2; ++h) {
                O[h][mt] = __builtin_amdgcn_mfma_f32_16x16x32_bf16(vf0, pf[h][0], O[h][mt], 0, 0, 0);
                O[h][mt] = __builtin_amdgcn_mfma_f32_16x16x32_bf16(vf1, pf[h][1], O[h][mt], 0, 0, 0);
            }
        }
    }

    // ---- partial epilogue: unnormalized O (bf16) + m,l ----
    const size_t jobbase = (size_t)b * NJOBS + jj;
#pragma unroll
    for (int h = 0; h < 2; ++h) {
        const int r = w * 32 + h * 16 + l16;
        unsigned short* po = Opart + jobbase * (128 * 128) + (size_t)r * 128;
#pragma unroll
        for (int mt = 0; mt < 8; ++mt) {
            short4v p;
            p[0] = (short)f2bf(O[h][mt][0]); p[1] = (short)f2bf(O[h][mt][1]);
            p[2] = (short)f2bf(O[h][mt][2]); p[3] = (short)f2bf(O[h][mt][3]);
            *(short4v*)&po[mt * 16 + quad * 4] = p;
        }
        if (quad == 0) {
            mbuf[jobbase * 128 + r] = m_run[h];
            lbuf[jobbase * 128 + r] = l_run[h];
        }
    }
}

// ---------------- Combine partials ----------------
// grid (32, 4) x 512 thr: thread -> q-row t>>2 (0..127), 32 head cols at (t&3)*32.
__global__ __launch_bounds__(512) void combine_kernel(
    const unsigned short* __restrict__ Opart, const float* __restrict__ mbuf,
    const float* __restrict__ lbuf, float* __restrict__ out)
{
    const int qi = blockIdx.x, b = blockIdx.y;
    const int nc = (qi + 5) / 5;
    int j0 = 0;
    for (int q = 0; q < qi; ++q) j0 += (q + 5) / 5;
    const int t = threadIdx.x;
    const int row = t >> 2, cg = (t & 3) * 32;

    float mv[MAXC], lv[MAXC];
    float M = -1e30f;
#pragma unroll
    for (int c2 = 0; c2 < MAXC; ++c2) {
        if (c2 < nc) {
            const size_t jb = (size_t)b * NJOBS + j0 + c2;
            mv[c2] = mbuf[jb * 128 + row];
            lv[c2] = lbuf[jb * 128 + row];
            M = fmaxf(M, mv[c2]);
        } else { mv[c2] = -1e30f; lv[c2] = 0.f; }
    }
    float L = 0.f;
#pragma unroll
    for (int c2 = 0; c2 < MAXC; ++c2)
        if (c2 < nc) L += __expf(mv[c2] - M) * lv[c2];
    const float Linv = 1.0f / L;

    float acc[32];
#pragma unroll
    for (int i = 0; i < 32; ++i) acc[i] = 0.f;
#pragma unroll
    for (int c2 = 0; c2 < MAXC; ++c2) {
        if (c2 < nc) {
            const float wgt = __expf(mv[c2] - M) * Linv;
            const unsigned short* po = Opart + ((size_t)b * NJOBS + j0 + c2) * (128 * 128) +
                                       (size_t)row * 128 + cg;
#pragma unroll
            for (int i = 0; i < 4; ++i) {
                i32x4 d = *(const i32x4*)&po[i * 8];
#pragma unroll
                for (int e = 0; e < 4; ++e) {
                    unsigned int u = (unsigned int)d[e];
                    acc[i * 8 + e * 2]     = fmaf(wgt, bf2f((unsigned short)(u & 0xffff)), acc[i * 8 + e * 2]);
                    acc[i * 8 + e * 2 + 1] = fmaf(wgt, bf2f((unsigned short)(u >> 16)),   acc[i * 8 + e * 2 + 1]);
                }
            }
        }
    }
    float* op = out + ((size_t)b * SEQ + qi * 128 + row) * HD + cg;
#pragma unroll
    for (int i = 0; i < 8; ++i) {
        float4 res;
        res.x = acc[i * 4]; res.y = acc[i * 4 + 1];
        res.z = acc[i * 4 + 2]; res.w = acc[i * 4 + 3];
        *(float4*)&op[i * 4] = res;
    }
}

extern "C" void kernel_launch(void* const* d_in, const int* in_sizes, int n_in,
                              void* d_out, int out_size, void* d_ws, size_t ws_size,
                              hipStream_t stream) {
    const float* x  = (const float*)d_in[0];
    const float* Wq = (const float*)d_in[1];
    const float* Wk = (const float*)d_in[2];
    const float* Wv = (const float*)d_in[3];

    unsigned short* qb    = (unsigned short*)d_ws;          // [16384][128] bf16
    unsigned short* kb    = qb  + (size_t)MROWS * HD;       // [16384][128] bf16
    unsigned short* vtb   = kb  + (size_t)MROWS * HD;       // [4][128][4096] bf16
    unsigned short* Wt    = vtb + (size_t)MROWS * HD;       // [3][128][1024] bf16
    unsigned short* Opart = Wt  + (size_t)3 * HD * EMB;     // [4][119][128][128] bf16
    float* mbuf = (float*)(Opart + (size_t)BATCH * NJOBS * 128 * 128);
    float* lbuf = mbuf + (size_t)BATCH * NJOBS * 128;
    float* out = (float*)d_out;

    wtrans_kernel <<<dim3(64, 3),  dim3(256), 0, stream>>>(Wq, Wk, Wv, Wt);
    qkv_kernel    <<<dim3(512),    dim3(512), 0, stream>>>(x, Wt, qb, kb, vtb);
    flash_kernel  <<<dim3(480),    dim3(256), 0, stream>>>(qb, kb, vtb, Opart, mbuf, lbuf);
    combine_kernel<<<dim3(32, 4),  dim3(512), 0, stream>>>(Opart, mbuf, lbuf, out);
}